// Round 1
// baseline (1132.294 us; speedup 1.0000x reference)
//
#include <hip/hip_runtime.h>
#include <math.h>

#define G_N 20000
#define NPAD 20032

static __device__ __forceinline__ float gelu_exact(float t) {
    // jax.nn.gelu(approximate=False) = 0.5*x*(1+erf(x/sqrt(2)))
    return 0.5f * t * (1.0f + erff(t * 0.70710678118654752440f));
}

// ---------------------------------------------------------------- zero
__global__ void __launch_bounds__(256) k_zero(float* a, int na, float* b, int nb) {
    int i = blockIdx.x * blockDim.x + threadIdx.x;
    int stride = gridDim.x * blockDim.x;
    for (int k = i; k < na; k += stride) a[k] = 0.0f;
    for (int k = i; k < nb; k += stride) b[k] = 0.0f;
}

// ---------------------------------------------------------------- pre-MLP: (x,coords) -> u_t[n][64]
__global__ void __launch_bounds__(256) k_pre(const float* __restrict__ x,
        const float* __restrict__ coords,
        const float* __restrict__ w1, const float* __restrict__ b1,
        const float* __restrict__ w2, const float* __restrict__ b2,
        float* __restrict__ ut) {
    int n = blockIdx.x * 256 + threadIdx.x;
    if (n >= G_N) return;
    float in5[5];
    in5[0] = x[n]; in5[1] = x[G_N + n]; in5[2] = x[2 * G_N + n];
    in5[3] = coords[n]; in5[4] = coords[G_N + n];
    float acc[64];
    #pragma unroll
    for (int c = 0; c < 64; ++c) acc[c] = b2[c];
    for (int o = 0; o < 128; ++o) {
        float t = b1[o];
        #pragma unroll
        for (int i = 0; i < 5; ++i) t = fmaf(in5[i], w1[i * 128 + o], t);
        float g = gelu_exact(t);
        const float4* w4 = (const float4*)(w2 + o * 64);
        #pragma unroll
        for (int q = 0; q < 16; ++q) {
            float4 w = w4[q];
            acc[q*4+0] = fmaf(g, w.x, acc[q*4+0]);
            acc[q*4+1] = fmaf(g, w.y, acc[q*4+1]);
            acc[q*4+2] = fmaf(g, w.z, acc[q*4+2]);
            acc[q*4+3] = fmaf(g, w.w, acc[q*4+3]);
        }
    }
    float4* outp = (float4*)(ut + (size_t)n * 64);
    #pragma unroll
    for (int q = 0; q < 16; ++q)
        outp[q] = make_float4(acc[q*4+0], acc[q*4+1], acc[q*4+2], acc[q*4+3]);
}

// ---------------------------------------------------------------- IPHI net + phasor tables
__device__ __forceinline__ void dense_layer(const float (*src)[64], float (*dst)[64],
        const float* __restrict__ W, const float* __restrict__ b,
        int K, int p, int og, bool do_tanh) {
    float acc[32];
    const int o0 = og * 32;
    #pragma unroll
    for (int oo = 0; oo < 32; ++oo) acc[oo] = b[o0 + oo];
    for (int i = 0; i < K; ++i) {
        float a = src[i][p];
        const float4* w4 = (const float4*)(W + i * 128 + o0);
        #pragma unroll
        for (int q = 0; q < 8; ++q) {
            float4 w = w4[q];
            acc[q*4+0] = fmaf(a, w.x, acc[q*4+0]);
            acc[q*4+1] = fmaf(a, w.y, acc[q*4+1]);
            acc[q*4+2] = fmaf(a, w.z, acc[q*4+2]);
            acc[q*4+3] = fmaf(a, w.w, acc[q*4+3]);
        }
    }
    if (do_tanh) {
        #pragma unroll
        for (int oo = 0; oo < 32; ++oo) dst[o0 + oo][p] = tanhf(acc[oo]);
    } else {
        #pragma unroll
        for (int oo = 0; oo < 32; ++oo) dst[o0 + oo][p] = acc[oo];
    }
}

__global__ void __launch_bounds__(256) k_iphi(const float* __restrict__ coords,
        const float* __restrict__ fc0w, const float* __restrict__ fc0b,
        const float* __restrict__ fncw, const float* __restrict__ fncb,
        const float* __restrict__ fc1w, const float* __restrict__ fc1b,
        const float* __restrict__ fc2w, const float* __restrict__ fc2b,
        const float* __restrict__ fc3w, const float* __restrict__ fc3b,
        const float* __restrict__ fc4w, const float* __restrict__ fc4b,
        float* __restrict__ ph) {
    __shared__ float act[2][128][64];  // [buf][feature][point]; stride 64: fixed-row access is conflict-free
    int t = threadIdx.x;
    int p = t & 63, og = t >> 6;       // og is wave-uniform
    int n = blockIdx.x * 64 + p;
    bool valid = n < G_N;
    float c0 = valid ? coords[n] : 0.5f;
    float c1 = valid ? coords[G_N + n] : 0.5f;
    float xc0 = c0 - 1e-4f, xc1 = c1 - 1e-4f;
    float ang = atan2f(xc1, xc0);
    float rad = sqrtf(fmaf(xc0, xc0, xc1 * xc1));
    float xd[4] = {c0, c1, ang, rad};
    const float PI_F = 3.14159274101257324f;
    if (og == 0) {
        for (int o = 0; o < 32; ++o) {
            float v = fc0b[o];
            #pragma unroll
            for (int i = 0; i < 4; ++i) v = fmaf(xd[i], fc0w[i * 32 + o], v);
            act[0][o][p] = v;
        }
    } else if (og == 1) {
        for (int d = 0; d < 4; ++d)
            #pragma unroll
            for (int j = 0; j < 8; ++j)
                act[0][32 + d * 8 + j][p] = sinf(xd[d] * (PI_F * (float)(1 << j)));
    } else if (og == 2) {
        for (int d = 0; d < 4; ++d)
            #pragma unroll
            for (int j = 0; j < 8; ++j)
                act[0][64 + d * 8 + j][p] = cosf(xd[d] * (PI_F * (float)(1 << j)));
    }
    __syncthreads();
    dense_layer(act[0], act[1], fncw, fncb, 96, p, og, false);  __syncthreads();
    dense_layer(act[1], act[0], fc1w, fc1b, 128, p, og, true);  __syncthreads();
    dense_layer(act[0], act[1], fc2w, fc2b, 128, p, og, true);  __syncthreads();
    dense_layer(act[1], act[0], fc3w, fc3b, 128, p, og, true);  __syncthreads();
    if (og == 0) {  // fc4: 128->2, then xphi = x + x*h
        float a0 = fc4b[0], a1 = fc4b[1];
        for (int i = 0; i < 128; ++i) {
            float a = act[0][i][p];
            a0 = fmaf(a, fc4w[i * 2 + 0], a0);
            a1 = fmaf(a, fc4w[i * 2 + 1], a1);
        }
        act[1][0][p] = fmaf(c0, a0, c0);
        act[1][1][p] = fmaf(c1, a1, c1);
    }
    __syncthreads();
    if (!valid) return;
    float xa = act[1][0][p], xb = act[1][1][p];
    const float TWO_PI = 6.28318548202514648f;
    float* phn = ph + (size_t)n * 96;
    // phasors stored with sign +1: e1[k]=exp(+2pi*i*xa*k1[k]), e2[k]=exp(+2pi*i*xb*k2[k])
    if (og == 0) {
        for (int k = 0; k < 12; ++k) {
            float s, c; sincosf(TWO_PI * (xa * (float)k), &s, &c);
            phn[2 * k] = c; phn[2 * k + 1] = s;
        }
    } else if (og == 1) {
        for (int k = 12; k < 24; ++k) {
            float s, c; sincosf(TWO_PI * (xa * (float)(k - 24)), &s, &c);
            phn[2 * k] = c; phn[2 * k + 1] = s;
        }
    } else if (og == 2) {
        for (int k = 0; k < 12; ++k) {
            float s, c; sincosf(TWO_PI * (xb * (float)k), &s, &c);
            phn[48 + 2 * k] = c; phn[48 + 2 * k + 1] = s;
        }
    } else {
        for (int k = 12; k < 23; ++k) {
            float s, c; sincosf(TWO_PI * (xb * (float)(k - 23)), &s, &c);
            phn[48 + 2 * k] = c; phn[48 + 2 * k + 1] = s;
        }
    }
}

// ---------------------------------------------------------------- project_in: u_ft[c][x*12+ky] (only ky 0..11 needed)
__global__ void __launch_bounds__(320) k_proj_in(const float* __restrict__ ut,
        const float* __restrict__ ph, float* __restrict__ uft) {
    int t = threadIdx.x;
    if (t >= 288) return;                 // no barriers in this kernel
    int chunk = blockIdx.x;               // 0..63
    int c0 = blockIdx.y * 16;             // channel group
    int xm = t / 12, ky = t % 12;
    float accr[16], acci[16];
    #pragma unroll
    for (int q = 0; q < 16; ++q) { accr[q] = 0.f; acci[q] = 0.f; }
    int n0 = chunk * 313;
    int n1 = n0 + 313; if (n1 > G_N) n1 = G_N;
    for (int n = n0; n < n1; ++n) {
        const float* phn = ph + (size_t)n * 96;
        float2 e1 = *(const float2*)(phn + 2 * xm);
        float2 e2 = *(const float2*)(phn + 48 + 2 * ky);
        // basis(-1) = conj(e1*e2)
        float br  =  e1.x * e2.x - e1.y * e2.y;
        float nbi = -(e1.x * e2.y + e1.y * e2.x);
        const float4* uv = (const float4*)(ut + (size_t)n * 64 + c0);
        #pragma unroll
        for (int q = 0; q < 4; ++q) {
            float4 u = uv[q];
            accr[q*4+0] = fmaf(u.x, br, accr[q*4+0]); acci[q*4+0] = fmaf(u.x, nbi, acci[q*4+0]);
            accr[q*4+1] = fmaf(u.y, br, accr[q*4+1]); acci[q*4+1] = fmaf(u.y, nbi, acci[q*4+1]);
            accr[q*4+2] = fmaf(u.z, br, accr[q*4+2]); acci[q*4+2] = fmaf(u.z, nbi, acci[q*4+2]);
            accr[q*4+3] = fmaf(u.w, br, accr[q*4+3]); acci[q*4+3] = fmaf(u.w, nbi, acci[q*4+3]);
        }
    }
    #pragma unroll
    for (int q = 0; q < 16; ++q) {
        atomicAdd(uft + ((size_t)(c0 + q) * 288 + t) * 2,     accr[q]);
        atomicAdd(uft + ((size_t)(c0 + q) * 288 + t) * 2 + 1, acci[q]);
    }
}

// ---------------------------------------------------------------- channel mix (pin) + 1/9216 fold
__global__ void __launch_bounds__(320) k_mix_in(const float* __restrict__ uft,
        const float* __restrict__ w1re, const float* __restrict__ w1im,
        const float* __restrict__ w2re, const float* __restrict__ w2im,
        float* __restrict__ fmix) {
    int t = threadIdx.x; if (t >= 288) return;
    int o = blockIdx.x;
    int xm = t / 12, ky = t % 12;
    const float *wre, *wim; int xl;
    if (xm < 12) { wre = w1re; wim = w1im; xl = xm; }
    else         { wre = w2re; wim = w2im; xl = xm - 12; }
    float fr = 0.f, fi = 0.f;
    for (int i = 0; i < 64; ++i) {
        float2 u = *(const float2*)(uft + ((size_t)i * 288 + t) * 2);
        int wi_ = ((i * 64 + o) * 12 + xl) * 12 + ky;
        float wr = wre[wi_], wq = wim[wi_];
        fr = fmaf(u.x, wr, fr); fr = fmaf(-u.y, wq, fr);
        fi = fmaf(u.x, wq, fi); fi = fmaf(u.y, wr, fi);
    }
    const float sc = 1.0f / 9216.0f;  // irfft2 normalization folded here
    fmix[((size_t)o * 288 + t) * 2]     = fr * sc;
    fmix[((size_t)o * 288 + t) * 2 + 1] = fi * sc;
}

// ---------------------------------------------------------------- sparse irfft2 -> uA[c][a][j]
__global__ void __launch_bounds__(384) k_igrid(const float* __restrict__ fmix,
        float* __restrict__ uA) {
    __shared__ float2 tw[96];
    __shared__ float2 Fs[288];
    __shared__ float2 T[12][96];
    int t = threadIdx.x, c = blockIdx.x;
    if (t < 96) {
        float s, co; sincosf(6.28318548202514648f * (float)t / 96.0f, &s, &co);
        tw[t] = make_float2(co, s);
    }
    if (t < 288) Fs[t] = *(const float2*)(fmix + ((size_t)c * 288 + t) * 2);
    __syncthreads();
    // stage B: T[ky][a] = sum_x F[x][ky] * e^{+2pi i k1[x] a/96}
    for (int q = 0; q < 3; ++q) {
        int idx = q * 384 + t;
        int kyy = idx / 96, a = idx % 96;
        float tr = 0.f, ti = 0.f;
        int m = 0;
        #pragma unroll
        for (int xx = 0; xx < 12; ++xx) {           // k1 = xx
            float2 w = tw[m]; float2 f = Fs[xx * 12 + kyy];
            tr += f.x * w.x - f.y * w.y;
            ti += f.x * w.y + f.y * w.x;
            m += a; if (m >= 96) m -= 96;
        }
        m = (84 * a) % 96;                          // k1m for xx=12 is 84
        #pragma unroll
        for (int xx = 12; xx < 24; ++xx) {          // k1 = xx-24
            float2 w = tw[m]; float2 f = Fs[xx * 12 + kyy];
            tr += f.x * w.x - f.y * w.y;
            ti += f.x * w.y + f.y * w.x;
            m += a; if (m >= 96) m -= 96;
        }
        T[kyy][a] = make_float2(tr, ti);
    }
    __syncthreads();
    // stage C: u[a][j] = Re T[0][a] + 2*sum_{ky>0} Re(T e^{+2pi i ky j/96})
    for (int q = 0; q < 24; ++q) {
        int idx = q * 384 + t;
        int a = idx / 96, j = idx % 96;
        float s = T[0][a].x;
        int m = j;
        #pragma unroll
        for (int kyy = 1; kyy < 12; ++kyy) {
            float2 w = tw[m]; float2 tt = T[kyy][a];
            s += 2.0f * (tt.x * w.x - tt.y * w.y);
            m += j; if (m >= 96) m -= 96;
        }
        uA[(size_t)c * 9216 + idx] = s;
    }
}

// ---------------------------------------------------------------- FFNO y-branch: uB = uA + invY(mix(dftY(uA)))
__global__ void __launch_bounds__(512) k_ffno_y(const float* __restrict__ uA,
        const float* __restrict__ wyre, const float* __restrict__ wyim,
        float* __restrict__ uB) {
    __shared__ float urow[64][97];
    __shared__ float2 Fy[64][12];
    __shared__ float2 Gy[64][12];
    __shared__ float2 tw[96];
    int t = threadIdx.x, a = blockIdx.x;
    if (t < 96) {
        float s, co; sincosf(6.28318548202514648f * (float)t / 96.0f, &s, &co);
        tw[t] = make_float2(co, s);
    }
    for (int q = 0; q < 12; ++q) {
        int idx = q * 512 + t;
        urow[idx / 96][idx % 96] = uA[(size_t)(idx / 96) * 9216 + a * 96 + (idx % 96)];
    }
    __syncthreads();
    for (int q = 0; q < 2; ++q) {
        int idx = q * 512 + t;
        if (idx < 768) {
            int i = idx / 12, ky = idx % 12;
            float fr = 0.f, fi = 0.f;
            int m = 0;
            for (int j = 0; j < 96; ++j) {          // forward: e^{-i}
                float u = urow[i][j];
                float2 w = tw[m];
                fr = fmaf(u, w.x, fr); fi = fmaf(-u, w.y, fi);
                m += ky; if (m >= 96) m -= 96;
            }
            Fy[i][ky] = make_float2(fr, fi);
        }
    }
    __syncthreads();
    for (int q = 0; q < 2; ++q) {
        int idx = q * 512 + t;
        if (idx < 768) {
            int o = idx / 12, ky = idx % 12;
            float gr = 0.f, gi = 0.f;
            for (int i = 0; i < 64; ++i) {
                float2 f = Fy[i][ky];
                int wi_ = (i * 64 + o) * 12 + ky;
                float wr = wyre[wi_], wq = wyim[wi_];
                gr += f.x * wr - f.y * wq;
                gi += f.x * wq + f.y * wr;
            }
            Gy[o][ky] = make_float2(gr, gi);
        }
    }
    __syncthreads();
    const float inv = 1.0f / 96.0f;
    for (int q = 0; q < 12; ++q) {
        int idx = q * 512 + t;
        int o = idx / 96, j = idx % 96;
        float s = Gy[o][0].x;
        int m = j;
        #pragma unroll
        for (int ky = 1; ky < 12; ++ky) {
            float2 g = Gy[o][ky]; float2 w = tw[m];
            s += 2.0f * (g.x * w.x - g.y * w.y);
            m += j; if (m >= 96) m -= 96;
        }
        uB[(size_t)o * 9216 + a * 96 + j] = urow[o][j] + s * inv;
    }
}

// ---------------------------------------------------------------- FFNO x-branch: uAout = uBin + invX(mix(dftX(uAin)))
__global__ void __launch_bounds__(512) k_ffno_x(const float* uAin,
        const float* __restrict__ wxre, const float* __restrict__ wxim,
        const float* __restrict__ uBin, float* uAout) {
    __shared__ float ucol[64][97];   // [c][a]
    __shared__ float2 Fx[64][12];
    __shared__ float2 Gx[64][12];
    __shared__ float2 tw[96];
    int t = threadIdx.x, j = blockIdx.x;
    if (t < 96) {
        float s, co; sincosf(6.28318548202514648f * (float)t / 96.0f, &s, &co);
        tw[t] = make_float2(co, s);
    }
    for (int q = 0; q < 12; ++q) {
        int idx = q * 512 + t;
        ucol[idx / 96][idx % 96] = uAin[(size_t)(idx / 96) * 9216 + (idx % 96) * 96 + j];
    }
    __syncthreads();
    for (int q = 0; q < 2; ++q) {
        int idx = q * 512 + t;
        if (idx < 768) {
            int i = idx / 12, kx = idx % 12;
            float fr = 0.f, fi = 0.f;
            int m = 0;
            for (int a = 0; a < 96; ++a) {
                float u = ucol[i][a];
                float2 w = tw[m];
                fr = fmaf(u, w.x, fr); fi = fmaf(-u, w.y, fi);
                m += kx; if (m >= 96) m -= 96;
            }
            Fx[i][kx] = make_float2(fr, fi);
        }
    }
    __syncthreads();
    for (int q = 0; q < 2; ++q) {
        int idx = q * 512 + t;
        if (idx < 768) {
            int o = idx / 12, kx = idx % 12;
            float gr = 0.f, gi = 0.f;
            for (int i = 0; i < 64; ++i) {
                float2 f = Fx[i][kx];
                int wi_ = (i * 64 + o) * 12 + kx;
                float wr = wxre[wi_], wq = wxim[wi_];
                gr += f.x * wr - f.y * wq;
                gi += f.x * wq + f.y * wr;
            }
            Gx[o][kx] = make_float2(gr, gi);
        }
    }
    __syncthreads();
    const float inv = 1.0f / 96.0f;
    for (int q = 0; q < 12; ++q) {
        int idx = q * 512 + t;
        int o = idx / 96, a = idx % 96;
        float s = Gx[o][0].x;
        int m = a;
        #pragma unroll
        for (int kx = 1; kx < 12; ++kx) {
            float2 g = Gx[o][kx]; float2 w = tw[m];
            s += 2.0f * (g.x * w.x - g.y * w.y);
            m += a; if (m >= 96) m -= 96;
        }
        uAout[(size_t)o * 9216 + a * 96 + j] = uBin[(size_t)o * 9216 + a * 96 + j] + s * inv;
    }
}

// ---------------------------------------------------------------- forward truncated rfft2 -> uftO[c][x*12+ky]
__global__ void __launch_bounds__(512) k_ogrid(const float* __restrict__ uA,
        float* __restrict__ uftO) {
    __shared__ float ug[96][97];
    __shared__ float2 P[12][97];
    __shared__ float2 tw[96];
    int t = threadIdx.x, c = blockIdx.x;
    if (t < 96) {
        float s, co; sincosf(6.28318548202514648f * (float)t / 96.0f, &s, &co);
        tw[t] = make_float2(co, s);
    }
    for (int q = 0; q < 18; ++q) {
        int idx = q * 512 + t;
        ug[idx / 96][idx % 96] = uA[(size_t)c * 9216 + idx];
    }
    __syncthreads();
    for (int q = 0; q < 3; ++q) {
        int idx = q * 512 + t;
        if (idx < 1152) {
            int ky = idx / 96, a = idx % 96;
            float fr = 0.f, fi = 0.f;
            int m = 0;
            for (int j = 0; j < 96; ++j) {
                float u = ug[a][j];
                float2 w = tw[m];
                fr = fmaf(u, w.x, fr); fi = fmaf(-u, w.y, fi);
                m += ky; if (m >= 96) m -= 96;
            }
            P[ky][a] = make_float2(fr, fi);
        }
    }
    __syncthreads();
    if (t < 288) {
        int x = t / 12, ky = t % 12;
        int k1m = (x < 12) ? x : (x + 72);
        float gr = 0.f, gi = 0.f;
        int m = 0;
        for (int a = 0; a < 96; ++a) {              // P * conj(tw)
            float2 p = P[ky][a];
            float2 w = tw[m];
            gr += p.x * w.x + p.y * w.y;
            gi += p.y * w.x - p.x * w.y;
            m += k1m; if (m >= 96) m -= 96;
        }
        uftO[((size_t)c * 288 + t) * 2]     = gr;
        uftO[((size_t)c * 288 + t) * 2 + 1] = gi;
    }
}

// ---------------------------------------------------------------- channel mix (pout) + Hermitian completion
__global__ void __launch_bounds__(320) k_mix_out(const float* __restrict__ uftO,
        const float* __restrict__ w1re, const float* __restrict__ w1im,
        const float* __restrict__ w2re, const float* __restrict__ w2im,
        float* __restrict__ ffull) {
    int t = threadIdx.x; if (t >= 288) return;
    int o = blockIdx.x;
    int xm = t / 12, ky = t % 12;
    const float *wre, *wim; int xl;
    if (xm < 12) { wre = w1re; wim = w1im; xl = xm; }
    else         { wre = w2re; wim = w2im; xl = xm - 12; }
    float fr = 0.f, fi = 0.f;
    for (int i = 0; i < 64; ++i) {
        float2 u = *(const float2*)(uftO + ((size_t)i * 288 + t) * 2);
        int wi_ = ((i * 64 + o) * 12 + xl) * 12 + ky;
        float wr = wre[wi_], wq = wim[wi_];
        fr = fmaf(u.x, wr, fr); fr = fmaf(-u.y, wq, fr);
        fi = fmaf(u.x, wq, fi); fi = fmaf(u.y, wr, fi);
    }
    int M = xm * 23 + ky;
    ffull[((size_t)M * 64 + o) * 2]     = fr;
    ffull[((size_t)M * 64 + o) * 2 + 1] = fi;
    if (ky > 0) {  // full_ft[23-x][23-ky] = conj(out_ft[x][ky])
        int Mc = (23 - xm) * 23 + (23 - ky);
        ffull[((size_t)Mc * 64 + o) * 2]     = fr;
        ffull[((size_t)Mc * 64 + o) * 2 + 1] = -fi;
    }
}

// ---------------------------------------------------------------- project_out (mode-split x4, atomic accum)
__global__ void __launch_bounds__(256) k_proj_out(const float* __restrict__ ffull,
        const float* __restrict__ ph, float* __restrict__ uout) {
    int n = blockIdx.x * 256 + threadIdx.x;
    if (n >= G_N) return;
    int mc = blockIdx.y;  // 0..3, 6 x-rows each (6*23=138 modes)
    float acc[64];
    #pragma unroll
    for (int q = 0; q < 64; ++q) acc[q] = 0.f;
    const float* phn = ph + (size_t)n * 96;
    int x0 = mc * 6;
    for (int x = x0; x < x0 + 6; ++x) {
        float2 e1 = *(const float2*)(phn + 2 * x);
        for (int y = 0; y < 23; ++y) {
            float2 e2 = *(const float2*)(phn + 48 + 2 * y);
            float br  = e1.x * e2.x - e1.y * e2.y;   // sign +1
            float nbi = -(e1.x * e2.y + e1.y * e2.x);
            const float4* Fv = (const float4*)(ffull + (size_t)(x * 23 + y) * 128);
            #pragma unroll
            for (int q = 0; q < 32; ++q) {
                float4 f = Fv[q];
                acc[q*2+0] = fmaf(f.x, br, acc[q*2+0]);
                acc[q*2+0] = fmaf(f.y, nbi, acc[q*2+0]);
                acc[q*2+1] = fmaf(f.z, br, acc[q*2+1]);
                acc[q*2+1] = fmaf(f.w, nbi, acc[q*2+1]);
            }
        }
    }
    #pragma unroll
    for (int cc = 0; cc < 64; ++cc)
        atomicAdd(uout + (size_t)cc * NPAD + n, acc[cc]);
}

// ---------------------------------------------------------------- head MLP -> out[3][G]
__global__ void __launch_bounds__(256) k_head(const float* __restrict__ uout,
        const float* __restrict__ w1, const float* __restrict__ b1,
        const float* __restrict__ w2, const float* __restrict__ b2,
        float* __restrict__ out) {
    int n = blockIdx.x * 256 + threadIdx.x;
    if (n >= G_N) return;
    float h[64];
    #pragma unroll
    for (int k = 0; k < 64; ++k) h[k] = b1[k];
    for (int c = 0; c < 64; ++c) {
        float av = uout[(size_t)c * NPAD + n];
        const float4* w4 = (const float4*)(w1 + c * 64);
        #pragma unroll
        for (int q = 0; q < 16; ++q) {
            float4 w = w4[q];
            h[q*4+0] = fmaf(av, w.x, h[q*4+0]);
            h[q*4+1] = fmaf(av, w.y, h[q*4+1]);
            h[q*4+2] = fmaf(av, w.z, h[q*4+2]);
            h[q*4+3] = fmaf(av, w.w, h[q*4+3]);
        }
    }
    float o0 = b2[0], o1 = b2[1], o2 = b2[2];
    #pragma unroll
    for (int k = 0; k < 64; ++k) {
        float g = gelu_exact(h[k]);
        o0 = fmaf(g, w2[k * 3 + 0], o0);
        o1 = fmaf(g, w2[k * 3 + 1], o1);
        o2 = fmaf(g, w2[k * 3 + 2], o2);
    }
    out[n] = o0; out[G_N + n] = o1; out[2 * G_N + n] = o2;
}

// ================================================================ launch
extern "C" void kernel_launch(void* const* d_in, const int* in_sizes, int n_in,
                              void* d_out, int out_size, void* d_ws, size_t ws_size,
                              hipStream_t stream) {
    const float* x        = (const float*)d_in[0];
    const float* coords   = (const float*)d_in[1];
    const float* pre_w1   = (const float*)d_in[2];
    const float* pre_b1   = (const float*)d_in[3];
    const float* pre_w2   = (const float*)d_in[4];
    const float* pre_b2   = (const float*)d_in[5];
    const float* pin_w1_re  = (const float*)d_in[6];
    const float* pin_w1_im  = (const float*)d_in[7];
    const float* pin_w2_re  = (const float*)d_in[8];
    const float* pin_w2_im  = (const float*)d_in[9];
    const float* pout_w1_re = (const float*)d_in[10];
    const float* pout_w1_im = (const float*)d_in[11];
    const float* pout_w2_re = (const float*)d_in[12];
    const float* pout_w2_im = (const float*)d_in[13];
    const float* ifc0w = (const float*)d_in[14];
    const float* ifc0b = (const float*)d_in[15];
    const float* ifncw = (const float*)d_in[16];
    const float* ifncb = (const float*)d_in[17];
    const float* ifc1w = (const float*)d_in[18];
    const float* ifc1b = (const float*)d_in[19];
    const float* ifc2w = (const float*)d_in[20];
    const float* ifc2b = (const float*)d_in[21];
    const float* ifc3w = (const float*)d_in[22];
    const float* ifc3b = (const float*)d_in[23];
    const float* ifc4w = (const float*)d_in[24];
    const float* ifc4b = (const float*)d_in[25];
    const float* wx_re = (const float*)d_in[26];
    const float* wx_im = (const float*)d_in[27];
    const float* wy_re = (const float*)d_in[28];
    const float* wy_im = (const float*)d_in[29];
    const float* hw1 = (const float*)d_in[30];
    const float* hb1 = (const float*)d_in[31];
    const float* hw2 = (const float*)d_in[32];
    const float* hb2 = (const float*)d_in[33];
    float* out = (float*)d_out;
    float* ws  = (float*)d_ws;

    float* ut    = ws + 0;        // [NPAD][64]
    float* ph    = ws + 1282048;  // [NPAD][96]
    float* uft   = ws + 3205120;  // [64][288][2]  (atomic, zeroed)
    float* fmix  = ws + 3241984;  // [64][288][2]
    float* uA    = ws + 3278848;  // [64][96][96]
    float* uB    = ws + 3868672;  // [64][96][96]
    float* uftO  = ws + 4458496;  // [64][288][2]
    float* ffull = ws + 4495360;  // [552][64][2]
    float* uout  = ws + 4566016;  // [64][NPAD]    (atomic, zeroed)

    k_zero<<<dim3(1024), dim3(256), 0, stream>>>(uft, 64 * 288 * 2, uout, 64 * NPAD);
    k_pre<<<dim3(79), dim3(256), 0, stream>>>(x, coords, pre_w1, pre_b1, pre_w2, pre_b2, ut);
    k_iphi<<<dim3(313), dim3(256), 0, stream>>>(coords, ifc0w, ifc0b, ifncw, ifncb,
            ifc1w, ifc1b, ifc2w, ifc2b, ifc3w, ifc3b, ifc4w, ifc4b, ph);
    k_proj_in<<<dim3(64, 4), dim3(320), 0, stream>>>(ut, ph, uft);
    k_mix_in<<<dim3(64), dim3(320), 0, stream>>>(uft, pin_w1_re, pin_w1_im, pin_w2_re, pin_w2_im, fmix);
    k_igrid<<<dim3(64), dim3(384), 0, stream>>>(fmix, uA);
    for (int L = 0; L < 4; ++L) {
        const float* lyre = wy_re + (size_t)L * 49152;
        const float* lyim = wy_im + (size_t)L * 49152;
        const float* lxre = wx_re + (size_t)L * 49152;
        const float* lxim = wx_im + (size_t)L * 49152;
        k_ffno_y<<<dim3(96), dim3(512), 0, stream>>>(uA, lyre, lyim, uB);
        k_ffno_x<<<dim3(96), dim3(512), 0, stream>>>(uA, lxre, lxim, uB, uA);
    }
    k_ogrid<<<dim3(64), dim3(512), 0, stream>>>(uA, uftO);
    k_mix_out<<<dim3(64), dim3(320), 0, stream>>>(uftO, pout_w1_re, pout_w1_im,
            pout_w2_re, pout_w2_im, ffull);
    k_proj_out<<<dim3(79, 4), dim3(256), 0, stream>>>(ffull, ph, uout);
    k_head<<<dim3(79), dim3(256), 0, stream>>>(uout, hw1, hb1, hw2, hb2, out);
}

// Round 2
// 838.346 us; speedup vs baseline: 1.3506x; 1.3506x over previous
//
#include <hip/hip_runtime.h>
#include <math.h>

#define G_N 20000
#define NPAD 20032

static __device__ __forceinline__ float gelu_exact(float t) {
    return 0.5f * t * (1.0f + erff(t * 0.70710678118654752440f));
}

// ---------------------------------------------------------------- zero
__global__ void __launch_bounds__(256) k_zero(float* a, int na, float* b, int nb) {
    int i = blockIdx.x * blockDim.x + threadIdx.x;
    int stride = gridDim.x * blockDim.x;
    for (int k = i; k < na; k += stride) a[k] = 0.0f;
    for (int k = i; k < nb; k += stride) b[k] = 0.0f;
}

// ---------------------------------------------------------------- pre-MLP: 4 threads/point, shfl reduce
__global__ void __launch_bounds__(256) k_pre(const float* __restrict__ x,
        const float* __restrict__ coords,
        const float* __restrict__ w1, const float* __restrict__ b1,
        const float* __restrict__ w2, const float* __restrict__ b2,
        float* __restrict__ ut) {
    int g = blockIdx.x * 256 + threadIdx.x;
    int n = g >> 2, sub = g & 3;
    bool valid = n < G_N;
    int nn = valid ? n : 0;
    float in5[5];
    in5[0] = x[nn]; in5[1] = x[G_N + nn]; in5[2] = x[2 * G_N + nn];
    in5[3] = coords[nn]; in5[4] = coords[G_N + nn];
    float acc[64];
    #pragma unroll
    for (int c = 0; c < 64; ++c) acc[c] = 0.0f;
    int h0 = sub * 32;
    for (int o = h0; o < h0 + 32; ++o) {
        float t = b1[o];
        #pragma unroll
        for (int i = 0; i < 5; ++i) t = fmaf(in5[i], w1[i * 128 + o], t);
        float gl = gelu_exact(t);
        const float4* w4 = (const float4*)(w2 + o * 64);
        #pragma unroll
        for (int q = 0; q < 16; ++q) {
            float4 w = w4[q];
            acc[q*4+0] = fmaf(gl, w.x, acc[q*4+0]);
            acc[q*4+1] = fmaf(gl, w.y, acc[q*4+1]);
            acc[q*4+2] = fmaf(gl, w.z, acc[q*4+2]);
            acc[q*4+3] = fmaf(gl, w.w, acc[q*4+3]);
        }
    }
    #pragma unroll
    for (int c = 0; c < 64; ++c) acc[c] += __shfl_xor(acc[c], 1);
    #pragma unroll
    for (int c = 0; c < 64; ++c) acc[c] += __shfl_xor(acc[c], 2);
    if (valid) {
        float4* op = (float4*)(ut + (size_t)n * 64 + sub * 16);
        #pragma unroll
        for (int q = 0; q < 4; ++q) {
            int c = sub * 16 + q * 4;
            op[q] = make_float4(acc[c] + b2[c], acc[c+1] + b2[c+1],
                                acc[c+2] + b2[c+2], acc[c+3] + b2[c+3]);
        }
    }
}

// ---------------------------------------------------------------- IPHI: tiled LDS GEMM, 64 pts/block
__shared__ float s_act[128][64];
__shared__ float s_wbuf[32][128];

__device__ __forceinline__ void iphi_gemm(const float* __restrict__ W,
        const float* __restrict__ b, int K, bool dotanh, int t) {
    int po = t & 15, oo = t >> 4;
    int o0 = oo * 8, p0 = po * 4;
    float acc[8][4];
    #pragma unroll
    for (int q = 0; q < 8; ++q)
        #pragma unroll
        for (int j = 0; j < 4; ++j) acc[q][j] = 0.0f;
    for (int kc = 0; kc < K; kc += 32) {
        __syncthreads();
        const float4* src = (const float4*)(W + (size_t)kc * 128);
        float4* dst = (float4*)&s_wbuf[0][0];
        #pragma unroll
        for (int i = 0; i < 4; ++i) dst[i * 256 + t] = src[i * 256 + t];
        __syncthreads();
        #pragma unroll 4
        for (int kk = 0; kk < 32; ++kk) {
            float4 a  = *(const float4*)&s_act[kc + kk][p0];
            float4 w0 = *(const float4*)&s_wbuf[kk][o0];
            float4 w1 = *(const float4*)&s_wbuf[kk][o0 + 4];
            float wv[8] = {w0.x, w0.y, w0.z, w0.w, w1.x, w1.y, w1.z, w1.w};
            float av[4] = {a.x, a.y, a.z, a.w};
            #pragma unroll
            for (int q = 0; q < 8; ++q)
                #pragma unroll
                for (int j = 0; j < 4; ++j)
                    acc[q][j] = fmaf(wv[q], av[j], acc[q][j]);
        }
    }
    __syncthreads();
    #pragma unroll
    for (int q = 0; q < 8; ++q) {
        float bo = b[o0 + q];
        float r0 = acc[q][0] + bo, r1 = acc[q][1] + bo;
        float r2 = acc[q][2] + bo, r3 = acc[q][3] + bo;
        if (dotanh) { r0 = tanhf(r0); r1 = tanhf(r1); r2 = tanhf(r2); r3 = tanhf(r3); }
        *(float4*)&s_act[o0 + q][p0] = make_float4(r0, r1, r2, r3);
    }
}

__global__ void __launch_bounds__(256) k_iphi(const float* __restrict__ coords,
        const float* __restrict__ fc0w, const float* __restrict__ fc0b,
        const float* __restrict__ fncw, const float* __restrict__ fncb,
        const float* __restrict__ fc1w, const float* __restrict__ fc1b,
        const float* __restrict__ fc2w, const float* __restrict__ fc2b,
        const float* __restrict__ fc3w, const float* __restrict__ fc3b,
        const float* __restrict__ fc4w, const float* __restrict__ fc4b,
        float* __restrict__ e1t, float* __restrict__ e2t) {
    __shared__ float xdl[4][64];
    __shared__ float ccs[2][64];
    __shared__ float xout[2][64];
    int t = threadIdx.x;
    int nb = blockIdx.x * 64;
    if (t < 64) {
        int n = nb + t; bool v = n < G_N;
        float c0 = v ? coords[n] : 0.5f;
        float c1 = v ? coords[G_N + n] : 0.5f;
        ccs[0][t] = c0; ccs[1][t] = c1;
        float xc0 = c0 - 1e-4f, xc1 = c1 - 1e-4f;
        xdl[0][t] = c0; xdl[1][t] = c1;
        xdl[2][t] = atan2f(xc1, xc0);
        xdl[3][t] = sqrtf(fmaf(xc0, xc0, xc1 * xc1));
    }
    __syncthreads();
    const float PI_F = 3.14159274101257324f;
    #pragma unroll
    for (int i = 0; i < 24; ++i) {
        int idx = i * 256 + t;
        int f = idx >> 6, p = idx & 63;
        float v;
        if (f < 32) {
            v = fc0b[f];
            #pragma unroll
            for (int d = 0; d < 4; ++d) v = fmaf(xdl[d][p], fc0w[d * 32 + f], v);
        } else {
            int ff = f - 32;
            int d = (ff >> 3) & 3, j = ff & 7;
            float arg = xdl[d][p] * (PI_F * (float)(1 << j));
            v = (f < 64) ? sinf(arg) : cosf(arg);
        }
        s_act[f][p] = v;
    }
    iphi_gemm(fncw, fncb,  96, false, t);
    iphi_gemm(fc1w, fc1b, 128, true,  t);
    iphi_gemm(fc2w, fc2b, 128, true,  t);
    iphi_gemm(fc3w, fc3b, 128, true,  t);
    __syncthreads();
    if (t < 128) {
        int o = t >> 6, p = t & 63;
        float a = fc4b[o];
        for (int k = 0; k < 128; ++k) a = fmaf(s_act[k][p], fc4w[k * 2 + o], a);
        float c = ccs[o][p];
        xout[o][p] = fmaf(c, a, c);
    }
    __syncthreads();
    int p = t & 63, og = t >> 6;
    int n = nb + p;
    if (n >= G_N) return;
    float xa = xout[0][p], xb = xout[1][p];
    const float TWO_PI = 6.28318548202514648f;
    float2* E1 = (float2*)e1t;
    float2* E2 = (float2*)e2t;
    if (og == 0) {
        for (int k = 0; k < 12; ++k) {
            float s, c; sincosf(TWO_PI * (xa * (float)k), &s, &c);
            E1[(size_t)k * NPAD + n] = make_float2(c, s);
        }
    } else if (og == 1) {
        for (int k = 12; k < 24; ++k) {
            float s, c; sincosf(TWO_PI * (xa * (float)(k - 24)), &s, &c);
            E1[(size_t)k * NPAD + n] = make_float2(c, s);
        }
    } else if (og == 2) {
        for (int k = 0; k < 12; ++k) {
            float s, c; sincosf(TWO_PI * (xb * (float)k), &s, &c);
            E2[(size_t)k * NPAD + n] = make_float2(c, s);
        }
    } else {
        for (int k = 12; k < 23; ++k) {
            float s, c; sincosf(TWO_PI * (xb * (float)(k - 23)), &s, &c);
            E2[(size_t)k * NPAD + n] = make_float2(c, s);
        }
    }
}

// ---------------------------------------------------------------- project_in (SoA phasors, 128 chunks)
__global__ void __launch_bounds__(320) k_proj_in(const float* __restrict__ ut,
        const float* __restrict__ e1t, const float* __restrict__ e2t,
        float* __restrict__ uft) {
    int t = threadIdx.x;
    if (t >= 288) return;
    int chunk = blockIdx.x;               // 0..127
    int c0 = blockIdx.y * 16;
    int xm = t / 12, ky = t % 12;
    const float2* E1 = (const float2*)e1t + (size_t)xm * NPAD;
    const float2* E2 = (const float2*)e2t + (size_t)ky * NPAD;
    float accr[16], acci[16];
    #pragma unroll
    for (int q = 0; q < 16; ++q) { accr[q] = 0.f; acci[q] = 0.f; }
    int n0 = chunk * 157;
    int n1 = n0 + 157; if (n1 > G_N) n1 = G_N;
    for (int n = n0; n < n1; ++n) {
        float2 e1 = E1[n];
        float2 e2 = E2[n];
        float br  =  e1.x * e2.x - e1.y * e2.y;
        float nbi = -(e1.x * e2.y + e1.y * e2.x);
        const float4* uv = (const float4*)(ut + (size_t)n * 64 + c0);
        #pragma unroll
        for (int q = 0; q < 4; ++q) {
            float4 u = uv[q];
            accr[q*4+0] = fmaf(u.x, br, accr[q*4+0]); acci[q*4+0] = fmaf(u.x, nbi, acci[q*4+0]);
            accr[q*4+1] = fmaf(u.y, br, accr[q*4+1]); acci[q*4+1] = fmaf(u.y, nbi, acci[q*4+1]);
            accr[q*4+2] = fmaf(u.z, br, accr[q*4+2]); acci[q*4+2] = fmaf(u.z, nbi, acci[q*4+2]);
            accr[q*4+3] = fmaf(u.w, br, accr[q*4+3]); acci[q*4+3] = fmaf(u.w, nbi, acci[q*4+3]);
        }
    }
    #pragma unroll
    for (int q = 0; q < 16; ++q) {
        atomicAdd(uft + ((size_t)(c0 + q) * 288 + t) * 2,     accr[q]);
        atomicAdd(uft + ((size_t)(c0 + q) * 288 + t) * 2 + 1, acci[q]);
    }
}

// ---------------------------------------------------------------- channel mix (pin) + 1/9216 fold
__global__ void __launch_bounds__(320) k_mix_in(const float* __restrict__ uft,
        const float* __restrict__ w1re, const float* __restrict__ w1im,
        const float* __restrict__ w2re, const float* __restrict__ w2im,
        float* __restrict__ fmix) {
    int t = threadIdx.x; if (t >= 288) return;
    int o = blockIdx.x;
    int xm = t / 12, ky = t % 12;
    const float *wre, *wim; int xl;
    if (xm < 12) { wre = w1re; wim = w1im; xl = xm; }
    else         { wre = w2re; wim = w2im; xl = xm - 12; }
    float fr = 0.f, fi = 0.f;
    for (int i = 0; i < 64; ++i) {
        float2 u = *(const float2*)(uft + ((size_t)i * 288 + t) * 2);
        int wi_ = ((i * 64 + o) * 12 + xl) * 12 + ky;
        float wr = wre[wi_], wq = wim[wi_];
        fr = fmaf(u.x, wr, fr); fr = fmaf(-u.y, wq, fr);
        fi = fmaf(u.x, wq, fi); fi = fmaf(u.y, wr, fi);
    }
    const float sc = 1.0f / 9216.0f;
    fmix[((size_t)o * 288 + t) * 2]     = fr * sc;
    fmix[((size_t)o * 288 + t) * 2 + 1] = fi * sc;
}

// ---------------------------------------------------------------- sparse irfft2 -> uY0, split over a-chunks
__global__ void __launch_bounds__(256) k_igrid(const float* __restrict__ fmix,
        float* __restrict__ uY) {
    __shared__ float2 tw[96];
    __shared__ float2 Fs[288];
    __shared__ float2 T[12][24];
    int t = threadIdx.x, c = blockIdx.x;
    int ac0 = blockIdx.y * 24;
    if (t < 96) {
        float s, co; sincosf(6.28318548202514648f * (float)t / 96.0f, &s, &co);
        tw[t] = make_float2(co, s);
    }
    for (int i = t; i < 288; i += 256)
        Fs[i] = *(const float2*)(fmix + ((size_t)c * 288 + i) * 2);
    __syncthreads();
    for (int i = t; i < 288; i += 256) {
        int kyy = i / 24, a = ac0 + (i % 24);
        float tr = 0.f, ti = 0.f;
        int m = 0;
        #pragma unroll
        for (int xx = 0; xx < 12; ++xx) {
            float2 w = tw[m]; float2 f = Fs[xx * 12 + kyy];
            tr += f.x * w.x - f.y * w.y;
            ti += f.x * w.y + f.y * w.x;
            m += a; if (m >= 96) m -= 96;
        }
        m = (84 * a) % 96;
        #pragma unroll
        for (int xx = 12; xx < 24; ++xx) {
            float2 w = tw[m]; float2 f = Fs[xx * 12 + kyy];
            tr += f.x * w.x - f.y * w.y;
            ti += f.x * w.y + f.y * w.x;
            m += a; if (m >= 96) m -= 96;
        }
        T[kyy][i % 24] = make_float2(tr, ti);
    }
    __syncthreads();
    for (int i = t; i < 2304; i += 256) {
        int al = i / 96, j = i % 96;
        float s = T[0][al].x;
        int m = j;
        #pragma unroll
        for (int kyy = 1; kyy < 12; ++kyy) {
            float2 w = tw[m]; float2 tt = T[kyy][al];
            s += 2.0f * (tt.x * w.x - tt.y * w.y);
            m += j; if (m >= 96) m -= 96;
        }
        uY[(size_t)c * 9216 + (ac0 + al) * 96 + j] = s;
    }
}

// ---------------------------------------------------------------- FFNO layer: y-branch (bz=0) + x-branch (bz=1)
__global__ void __launch_bounds__(512) k_ffno(const float* __restrict__ uYin,
        const float* __restrict__ uXin,
        const float* __restrict__ wyre, const float* __restrict__ wyim,
        const float* __restrict__ wxre, const float* __restrict__ wxim,
        float* __restrict__ uYout, float* __restrict__ uXout) {
    __shared__ float us[64][97];
    __shared__ float2 F[64][12];
    __shared__ float2 Gm[64][12];
    __shared__ float2 tw[96];
    int t = threadIdx.x;
    int brn = blockIdx.y;   // 0: y-branch (row a=bx), 1: x-branch (col j=bx)
    int bx = blockIdx.x;
    if (t < 96) {
        float s, co; sincosf(6.28318548202514648f * (float)t / 96.0f, &s, &co);
        tw[t] = make_float2(co, s);
    }
    if (brn == 0) {
        for (int q = 0; q < 12; ++q) {
            int idx = q * 512 + t;
            size_t gi = (size_t)(idx / 96) * 9216 + bx * 96 + (idx % 96);
            us[idx / 96][idx % 96] = uYin[gi] + uXin[gi];
        }
    } else {
        for (int q = 0; q < 12; ++q) {
            int idx = q * 512 + t;
            size_t gi = (size_t)(idx / 96) * 9216 + (idx % 96) * 96 + bx;
            us[idx / 96][idx % 96] = uYin[gi] + uXin[gi];
        }
    }
    const float* wre = (brn == 0) ? wyre : wxre;
    const float* wim = (brn == 0) ? wyim : wxim;
    __syncthreads();
    for (int q = 0; q < 2; ++q) {
        int idx = q * 512 + t;
        if (idx < 768) {
            int i = idx / 12, k = idx % 12;
            float fr = 0.f, fi = 0.f;
            int m = 0;
            for (int s = 0; s < 96; ++s) {
                float u = us[i][s];
                float2 w = tw[m];
                fr = fmaf(u, w.x, fr); fi = fmaf(-u, w.y, fi);
                m += k; if (m >= 96) m -= 96;
            }
            F[i][k] = make_float2(fr, fi);
        }
    }
    __syncthreads();
    for (int q = 0; q < 2; ++q) {
        int idx = q * 512 + t;
        if (idx < 768) {
            int o = idx / 12, k = idx % 12;
            float gr = 0.f, gi = 0.f;
            for (int i = 0; i < 64; ++i) {
                float2 f = F[i][k];
                int wi_ = (i * 64 + o) * 12 + k;
                float wr = wre[wi_], wq = wim[wi_];
                gr += f.x * wr - f.y * wq;
                gi += f.x * wq + f.y * wr;
            }
            Gm[o][k] = make_float2(gr, gi);
        }
    }
    __syncthreads();
    const float inv = 1.0f / 96.0f;
    for (int q = 0; q < 12; ++q) {
        int idx = q * 512 + t;
        int o = idx / 96, s = idx % 96;
        float v = Gm[o][0].x;
        int m = s;
        #pragma unroll
        for (int k = 1; k < 12; ++k) {
            float2 g = Gm[o][k]; float2 w = tw[m];
            v += 2.0f * (g.x * w.x - g.y * w.y);
            m += s; if (m >= 96) m -= 96;
        }
        if (brn == 0)
            uYout[(size_t)o * 9216 + bx * 96 + s] = us[o][s] + v * inv;
        else
            uXout[(size_t)o * 9216 + s * 96 + bx] = v * inv;
    }
}

// ---------------------------------------------------------------- forward truncated rfft2 -> uftO
__global__ void __launch_bounds__(512) k_ogrid(const float* __restrict__ uY,
        const float* __restrict__ uX, float* __restrict__ uftO) {
    __shared__ float ug[96][97];
    __shared__ float2 P[12][97];
    __shared__ float2 tw[96];
    int t = threadIdx.x, c = blockIdx.x;
    if (t < 96) {
        float s, co; sincosf(6.28318548202514648f * (float)t / 96.0f, &s, &co);
        tw[t] = make_float2(co, s);
    }
    for (int q = 0; q < 18; ++q) {
        int idx = q * 512 + t;
        size_t gi = (size_t)c * 9216 + idx;
        ug[idx / 96][idx % 96] = uY[gi] + uX[gi];
    }
    __syncthreads();
    for (int q = 0; q < 3; ++q) {
        int idx = q * 512 + t;
        if (idx < 1152) {
            int ky = idx / 96, a = idx % 96;
            float fr = 0.f, fi = 0.f;
            int m = 0;
            for (int j = 0; j < 96; ++j) {
                float u = ug[a][j];
                float2 w = tw[m];
                fr = fmaf(u, w.x, fr); fi = fmaf(-u, w.y, fi);
                m += ky; if (m >= 96) m -= 96;
            }
            P[ky][a] = make_float2(fr, fi);
        }
    }
    __syncthreads();
    if (t < 288) {
        int x = t / 12, ky = t % 12;
        int k1m = (x < 12) ? x : (x + 72);
        float gr = 0.f, gi = 0.f;
        int m = 0;
        for (int a = 0; a < 96; ++a) {
            float2 p = P[ky][a];
            float2 w = tw[m];
            gr += p.x * w.x + p.y * w.y;
            gi += p.y * w.x - p.x * w.y;
            m += k1m; if (m >= 96) m -= 96;
        }
        uftO[((size_t)c * 288 + t) * 2]     = gr;
        uftO[((size_t)c * 288 + t) * 2 + 1] = gi;
    }
}

// ---------------------------------------------------------------- channel mix (pout) + Hermitian completion
__global__ void __launch_bounds__(320) k_mix_out(const float* __restrict__ uftO,
        const float* __restrict__ w1re, const float* __restrict__ w1im,
        const float* __restrict__ w2re, const float* __restrict__ w2im,
        float* __restrict__ ffull) {
    int t = threadIdx.x; if (t >= 288) return;
    int o = blockIdx.x;
    int xm = t / 12, ky = t % 12;
    const float *wre, *wim; int xl;
    if (xm < 12) { wre = w1re; wim = w1im; xl = xm; }
    else         { wre = w2re; wim = w2im; xl = xm - 12; }
    float fr = 0.f, fi = 0.f;
    for (int i = 0; i < 64; ++i) {
        float2 u = *(const float2*)(uftO + ((size_t)i * 288 + t) * 2);
        int wi_ = ((i * 64 + o) * 12 + xl) * 12 + ky;
        float wr = wre[wi_], wq = wim[wi_];
        fr = fmaf(u.x, wr, fr); fr = fmaf(-u.y, wq, fr);
        fi = fmaf(u.x, wq, fi); fi = fmaf(u.y, wr, fi);
    }
    int M = xm * 23 + ky;
    ffull[((size_t)M * 64 + o) * 2]     = fr;
    ffull[((size_t)M * 64 + o) * 2 + 1] = fi;
    if (ky > 0) {
        int Mc = (23 - xm) * 23 + (23 - ky);
        ffull[((size_t)Mc * 64 + o) * 2]     = fr;
        ffull[((size_t)Mc * 64 + o) * 2 + 1] = -fi;
    }
}

// ---------------------------------------------------------------- project_out (channel-split x8, no atomics)
__global__ void __launch_bounds__(256) k_proj_out(const float* __restrict__ ffull,
        const float* __restrict__ e1t, const float* __restrict__ e2t,
        float* __restrict__ uout) {
    int n = blockIdx.x * 256 + threadIdx.x;
    if (n >= G_N) return;
    int c0 = blockIdx.y * 8;   // 8 channels per block
    float acc[8];
    #pragma unroll
    for (int q = 0; q < 8; ++q) acc[q] = 0.f;
    const float2* E1 = (const float2*)e1t;
    const float2* E2 = (const float2*)e2t;
    for (int x = 0; x < 24; ++x) {
        float2 e1 = E1[(size_t)x * NPAD + n];
        for (int y = 0; y < 23; ++y) {
            float2 e2 = E2[(size_t)y * NPAD + n];
            float br  =  e1.x * e2.x - e1.y * e2.y;
            float nbi = -(e1.x * e2.y + e1.y * e2.x);
            const float4* Fv = (const float4*)(ffull + ((size_t)(x * 23 + y) * 64 + c0) * 2);
            #pragma unroll
            for (int q = 0; q < 4; ++q) {
                float4 f = Fv[q];
                acc[q*2+0] = fmaf(f.x, br, acc[q*2+0]);
                acc[q*2+0] = fmaf(f.y, nbi, acc[q*2+0]);
                acc[q*2+1] = fmaf(f.z, br, acc[q*2+1]);
                acc[q*2+1] = fmaf(f.w, nbi, acc[q*2+1]);
            }
        }
    }
    #pragma unroll
    for (int q = 0; q < 8; ++q)
        uout[(size_t)(c0 + q) * NPAD + n] = acc[q];
}

// ---------------------------------------------------------------- head MLP -> out[3][G]
__global__ void __launch_bounds__(256) k_head(const float* __restrict__ uout,
        const float* __restrict__ w1, const float* __restrict__ b1,
        const float* __restrict__ w2, const float* __restrict__ b2,
        float* __restrict__ out) {
    int n = blockIdx.x * 256 + threadIdx.x;
    if (n >= G_N) return;
    float h[64];
    #pragma unroll
    for (int k = 0; k < 64; ++k) h[k] = b1[k];
    for (int c = 0; c < 64; ++c) {
        float av = uout[(size_t)c * NPAD + n];
        const float4* w4 = (const float4*)(w1 + c * 64);
        #pragma unroll
        for (int q = 0; q < 16; ++q) {
            float4 w = w4[q];
            h[q*4+0] = fmaf(av, w.x, h[q*4+0]);
            h[q*4+1] = fmaf(av, w.y, h[q*4+1]);
            h[q*4+2] = fmaf(av, w.z, h[q*4+2]);
            h[q*4+3] = fmaf(av, w.w, h[q*4+3]);
        }
    }
    float o0 = b2[0], o1 = b2[1], o2 = b2[2];
    #pragma unroll
    for (int k = 0; k < 64; ++k) {
        float g = gelu_exact(h[k]);
        o0 = fmaf(g, w2[k * 3 + 0], o0);
        o1 = fmaf(g, w2[k * 3 + 1], o1);
        o2 = fmaf(g, w2[k * 3 + 2], o2);
    }
    out[n] = o0; out[G_N + n] = o1; out[2 * G_N + n] = o2;
}

// ================================================================ launch
extern "C" void kernel_launch(void* const* d_in, const int* in_sizes, int n_in,
                              void* d_out, int out_size, void* d_ws, size_t ws_size,
                              hipStream_t stream) {
    const float* x        = (const float*)d_in[0];
    const float* coords   = (const float*)d_in[1];
    const float* pre_w1   = (const float*)d_in[2];
    const float* pre_b1   = (const float*)d_in[3];
    const float* pre_w2   = (const float*)d_in[4];
    const float* pre_b2   = (const float*)d_in[5];
    const float* pin_w1_re  = (const float*)d_in[6];
    const float* pin_w1_im  = (const float*)d_in[7];
    const float* pin_w2_re  = (const float*)d_in[8];
    const float* pin_w2_im  = (const float*)d_in[9];
    const float* pout_w1_re = (const float*)d_in[10];
    const float* pout_w1_im = (const float*)d_in[11];
    const float* pout_w2_re = (const float*)d_in[12];
    const float* pout_w2_im = (const float*)d_in[13];
    const float* ifc0w = (const float*)d_in[14];
    const float* ifc0b = (const float*)d_in[15];
    const float* ifncw = (const float*)d_in[16];
    const float* ifncb = (const float*)d_in[17];
    const float* ifc1w = (const float*)d_in[18];
    const float* ifc1b = (const float*)d_in[19];
    const float* ifc2w = (const float*)d_in[20];
    const float* ifc2b = (const float*)d_in[21];
    const float* ifc3w = (const float*)d_in[22];
    const float* ifc3b = (const float*)d_in[23];
    const float* ifc4w = (const float*)d_in[24];
    const float* ifc4b = (const float*)d_in[25];
    const float* wx_re = (const float*)d_in[26];
    const float* wx_im = (const float*)d_in[27];
    const float* wy_re = (const float*)d_in[28];
    const float* wy_im = (const float*)d_in[29];
    const float* hw1 = (const float*)d_in[30];
    const float* hb1 = (const float*)d_in[31];
    const float* hw2 = (const float*)d_in[32];
    const float* hb2 = (const float*)d_in[33];
    float* out = (float*)d_out;
    float* ws  = (float*)d_ws;

    // lifetimes allow aliases: ffull in ut's region; uftO in uft's; uout over uYb/uXb
    float* ut    = ws + 0;          // [NPAD][64]              (dead after proj_in)
    float* ffull = ws + 0;          // [552][64][2]            (alias: written by mix_out)
    float* e1t   = ws + 1282048;    // [24][NPAD] float2
    float* e2t   = ws + 2243584;    // [23][NPAD] float2
    float* uft   = ws + 3165056;    // [64][288][2]  atomic, zeroed; later reused as uftO
    float* fmix  = ws + 3201920;    // [64][288][2]
    float* uYa   = ws + 3238784;    // [64][96][96]
    float* uXa   = ws + 3828608;    // [64][96][96]  zeroed (layer-0 deferred-sum partner)
    float* uYb   = ws + 4418432;    // [64][96][96]
    float* uXb   = ws + 5008256;    // [64][96][96]
    float* uout  = ws + 4418432;    // [64][NPAD]    (alias over uYb/uXb, dead by then)

    k_zero<<<dim3(1024), dim3(256), 0, stream>>>(uft, 64 * 288 * 2, uXa, 64 * 96 * 96);
    k_pre<<<dim3(313), dim3(256), 0, stream>>>(x, coords, pre_w1, pre_b1, pre_w2, pre_b2, ut);
    k_iphi<<<dim3(313), dim3(256), 0, stream>>>(coords, ifc0w, ifc0b, ifncw, ifncb,
            ifc1w, ifc1b, ifc2w, ifc2b, ifc3w, ifc3b, ifc4w, ifc4b, e1t, e2t);
    k_proj_in<<<dim3(128, 4), dim3(320), 0, stream>>>(ut, e1t, e2t, uft);
    k_mix_in<<<dim3(64), dim3(320), 0, stream>>>(uft, pin_w1_re, pin_w1_im, pin_w2_re, pin_w2_im, fmix);
    k_igrid<<<dim3(64, 4), dim3(256), 0, stream>>>(fmix, uYa);
    {
        const float* yi = uYa; const float* xi = uXa;
        float* yo = uYb; float* xo = uXb;
        for (int L = 0; L < 4; ++L) {
            k_ffno<<<dim3(96, 2), dim3(512), 0, stream>>>(yi, xi,
                    wy_re + (size_t)L * 49152, wy_im + (size_t)L * 49152,
                    wx_re + (size_t)L * 49152, wx_im + (size_t)L * 49152,
                    yo, xo);
            const float* ty = yo; const float* tx = xo;
            yo = (float*)yi; xo = (float*)xi;
            yi = ty; xi = tx;
        }
        // after 4 layers result is in (uYa, uXa)
    }
    k_ogrid<<<dim3(64), dim3(512), 0, stream>>>(uYa, uXa, uft /*as uftO*/);
    k_mix_out<<<dim3(64), dim3(320), 0, stream>>>(uft, pout_w1_re, pout_w1_im,
            pout_w2_re, pout_w2_im, ffull);
    k_proj_out<<<dim3(79, 8), dim3(256), 0, stream>>>(ffull, e1t, e2t, uout);
    k_head<<<dim3(79), dim3(256), 0, stream>>>(uout, hw1, hb1, hw2, hb2, out);
}